// Round 1
// baseline (196.286 us; speedup 1.0000x reference)
//
#include <hip/hip_runtime.h>

// SSIM loss, fused single-pass implementation.
// B=32, C=1, H=W=512, window 11x11 separable Gaussian.
#define B_  32
#define H_  512
#define W_  512
#define WS_ 11
#define R_  5            // window radius
#define TW  64           // tile width  (output)
#define TH  16           // tile height (output)
#define HWT (TW + 2*R_)  // 74  halo tile width
#define HHT (TH + 2*R_)  // 26  halo tile height

__global__ __launch_bounds__(256)
void ssim_main(const float* __restrict__ pred,
               const float* __restrict__ targ,
               const float* __restrict__ win,
               double* __restrict__ acc)
{
    __shared__ float g[WS_];
    __shared__ float sp[HHT][HWT];   // raw pred tile (+halo)
    __shared__ float st[HHT][HWT];   // raw target tile (+halo)
    __shared__ float h0[HHT][TW];    // horiz-blurred p
    __shared__ float h1[HHT][TW];    // horiz-blurred t
    __shared__ float h2[HHT][TW];    // horiz-blurred p^2
    __shared__ float h3[HHT][TW];    // horiz-blurred t^2
    __shared__ float h4[HHT][TW];    // horiz-blurred p*t
    __shared__ float wsum[4];

    const int tid = threadIdx.x;
    const int tilesX = W_ / TW;   // 8
    const int tilesY = H_ / TH;   // 32
    int bid = blockIdx.x;
    const int b   = bid / (tilesX * tilesY);
    int rem       = bid % (tilesX * tilesY);
    const int ty  = rem / tilesX;
    const int tx  = rem % tilesX;
    const int x0  = tx * TW - R_;
    const int y0  = ty * TH - R_;

    // Recover 1-D gaussian: row sums of the 2-D window (sum(g)==1 so
    // rowsum_i = g_i exactly, up to fp rounding).
    if (tid < WS_) {
        float s = 0.f;
        #pragma unroll
        for (int j = 0; j < WS_; ++j) s += win[tid * WS_ + j];
        g[tid] = s;
    }

    const float* pb = pred + (size_t)b * (H_ * W_);
    const float* tb = targ + (size_t)b * (H_ * W_);

    // Stage raw tiles (zero padding outside image == SAME conv semantics).
    for (int i = tid; i < HHT * HWT; i += 256) {
        int ly = i / HWT, lx = i - ly * HWT;
        int gy = y0 + ly, gx = x0 + lx;
        float p = 0.f, t = 0.f;
        if ((unsigned)gy < (unsigned)H_ && (unsigned)gx < (unsigned)W_) {
            size_t off = (size_t)gy * W_ + gx;
            p = pb[off];
            t = tb[off];
        }
        sp[ly][lx] = p;
        st[ly][lx] = t;
    }
    __syncthreads();

    // Horizontal pass: 5 quantities at once.
    for (int i = tid; i < HHT * TW; i += 256) {
        int ly = i >> 6, lx = i & 63;
        float a0 = 0.f, a1 = 0.f, a2 = 0.f, a3 = 0.f, a4 = 0.f;
        #pragma unroll
        for (int k = 0; k < WS_; ++k) {
            float w = g[k];
            float p = sp[ly][lx + k];
            float t = st[ly][lx + k];
            float wp = w * p;
            float wt = w * t;
            a0 += wp;
            a1 += wt;
            a2 = fmaf(wp, p, a2);
            a3 = fmaf(wt, t, a3);
            a4 = fmaf(wp, t, a4);
        }
        h0[ly][lx] = a0;
        h1[ly][lx] = a1;
        h2[ly][lx] = a2;
        h3[ly][lx] = a3;
        h4[ly][lx] = a4;
    }
    __syncthreads();

    // Vertical pass + SSIM map + local sum.
    float lsum = 0.f;
    for (int i = tid; i < TH * TW; i += 256) {
        int ly = i >> 6, lx = i & 63;
        float mp = 0.f, mt = 0.f, vp = 0.f, vt = 0.f, cv = 0.f;
        #pragma unroll
        for (int k = 0; k < WS_; ++k) {
            float w = g[k];
            mp = fmaf(w, h0[ly + k][lx], mp);
            mt = fmaf(w, h1[ly + k][lx], mt);
            vp = fmaf(w, h2[ly + k][lx], vp);
            vt = fmaf(w, h3[ly + k][lx], vt);
            cv = fmaf(w, h4[ly + k][lx], cv);
        }
        float mp2 = mp * mp, mt2 = mt * mt, mpt = mp * mt;
        float sp2 = fmaxf(vp - mp2, 0.f);
        float st2 = fmaxf(vt - mt2, 0.f);
        float spt = cv - mpt;
        float num = (2.f * mpt + 1e-4f) * (2.f * spt + 9e-4f);
        float den = (mp2 + mt2 + 1e-4f) * (sp2 + st2 + 9e-4f);
        lsum += num / (den + 1e-8f);
    }

    // Wave (64-lane) shuffle reduce, then cross-wave via LDS, then one
    // double atomic per block.
    #pragma unroll
    for (int off = 32; off > 0; off >>= 1)
        lsum += __shfl_down(lsum, off, 64);
    int wid = tid >> 6, lane = tid & 63;
    if (lane == 0) wsum[wid] = lsum;
    __syncthreads();
    if (tid == 0) {
        double s = (double)wsum[0] + (double)wsum[1]
                 + (double)wsum[2] + (double)wsum[3];
        atomicAdd(acc, s);
    }
}

__global__ void ssim_final(const double* __restrict__ acc,
                           float* __restrict__ out)
{
    const double n = (double)B_ * (double)H_ * (double)W_;
    out[0] = (float)(1.0 - acc[0] / n);
}

extern "C" void kernel_launch(void* const* d_in, const int* in_sizes, int n_in,
                              void* d_out, int out_size, void* d_ws, size_t ws_size,
                              hipStream_t stream)
{
    const float* pred = (const float*)d_in[0];
    const float* targ = (const float*)d_in[1];
    const float* win  = (const float*)d_in[2];
    float* out  = (float*)d_out;
    double* acc = (double*)d_ws;

    hipMemsetAsync(acc, 0, sizeof(double), stream);

    const int nblocks = B_ * (W_ / TW) * (H_ / TH);  // 32*8*32 = 8192
    ssim_main<<<nblocks, 256, 0, stream>>>(pred, targ, win, acc);
    ssim_final<<<1, 1, 0, stream>>>(acc, out);
}

// Round 2
// 186.628 us; speedup vs baseline: 1.0517x; 1.0517x over previous
//
#include <hip/hip_runtime.h>

// Fused SSIM loss. B=32, C=1, 512x512, 11x11 separable Gaussian.
// One kernel: stage raw p/t tile (+halo) in LDS, per-thread horizontal
// blur, register-resident vertical scatter (5x16 accumulators/thread),
// SSIM map, block reduce, atomic + ticket finisher (no second kernel).
#define B_   32
#define H_   512
#define W_   512
#define R_   5
#define TW   64
#define TH   64
#define S_   16             // output rows per thread strip
#define HHT  (TH + 2*R_)    // 74 raw tile rows
#define HWT  (TW + 2*R_)    // 74 raw tile cols used
#define LDW  76             // LDS row stride (floats)
#define NBLK (B_ * (W_/TW) * (H_/TH))   // 32*8*8 = 2048

__global__ __launch_bounds__(256, 3)
void ssim_fused(const float* __restrict__ pred,
                const float* __restrict__ targ,
                const float* __restrict__ win,
                double* __restrict__ acc,
                unsigned int* __restrict__ cnt,
                float* __restrict__ out)
{
    __shared__ float sp[HHT][LDW];
    __shared__ float st[HHT][LDW];
    __shared__ float wg[12];
    __shared__ float wsum[4];

    const int tid = threadIdx.x;
    // grid: bid = ((b*8)+ty)*8+tx  (8x8 tiles of 64x64, 32 batches)
    const int bid = blockIdx.x;
    const int b   = bid >> 6;
    const int rem = bid & 63;
    const int ty  = rem >> 3;
    const int tx  = rem & 7;
    const int x0  = tx * TW - R_;   // global col of tile col 0
    const int y0  = ty * TH - R_;   // global row of tile row 0

    // 1-D gaussian = row sums of the 2-D window (window sums to 1).
    if (tid < 11) {
        float s = 0.f;
        #pragma unroll
        for (int j = 0; j < 11; ++j) s += win[tid * 11 + j];
        wg[tid] = s;
    }

    const float* pb = pred + (size_t)b * (H_ * W_);
    const float* tb = targ + (size_t)b * (H_ * W_);

    // ---- Stage raw tiles (zero pad outside image == SAME conv). ----
    {
        const int c  = tid & 127;     // 0..127 (cols; only 0..73 used)
        const int r0 = tid >> 7;      // 0..1
        if (c < HWT) {
            const int gx = x0 + c;
            const bool xok = (unsigned)gx < (unsigned)W_;
            for (int r = r0; r < HHT; r += 2) {
                const int gy = y0 + r;
                float p = 0.f, t = 0.f;
                if (xok && (unsigned)gy < (unsigned)H_) {
                    const size_t off = (size_t)gy * W_ + gx;
                    p = pb[off];
                    t = tb[off];
                }
                sp[r][c] = p;
                st[r][c] = t;
            }
        }
    }
    __syncthreads();

    // weights into registers (broadcast reads)
    float w[11];
    #pragma unroll
    for (int k = 0; k < 11; ++k) w[k] = wg[k];

    // ---- Horizontal blur + vertical register scatter. ----
    // Thread = (lane lx: output col, strip s: rows [16s,16s+16)).
    const int lx = tid & 63;
    const int ss = tid >> 6;      // 0..3
    const int rbase = ss * S_;    // first raw row this strip touches

    float a0[S_], a1[S_], a2[S_], a3[S_], a4[S_];
    #pragma unroll
    for (int o = 0; o < S_; ++o) {
        a0[o] = 0.f; a1[o] = 0.f; a2[o] = 0.f; a3[o] = 0.f; a4[o] = 0.f;
    }

    #pragma unroll
    for (int j = 0; j < S_ + 2 * R_; ++j) {   // 26 h-rows
        const float* prow = &sp[rbase + j][lx];
        const float* trow = &st[rbase + j][lx];
        float h0 = 0.f, h1 = 0.f, h2 = 0.f, h3 = 0.f, h4 = 0.f;
        #pragma unroll
        for (int k = 0; k < 11; ++k) {
            const float p = prow[k];
            const float t = trow[k];
            const float wv = w[k];
            const float wp = wv * p;
            const float wt = wv * t;
            h0 += wp;
            h1 += wt;
            h2 = fmaf(wp, p, h2);
            h3 = fmaf(wt, t, h3);
            h4 = fmaf(wp, t, h4);
        }
        // scatter into pending outputs: output o uses h-rows o..o+10
        #pragma unroll
        for (int o = 0; o < S_; ++o) {
            const int k = j - o;
            if (k >= 0 && k < 11) {
                const float wv = w[k];
                a0[o] = fmaf(wv, h0, a0[o]);
                a1[o] = fmaf(wv, h1, a1[o]);
                a2[o] = fmaf(wv, h2, a2[o]);
                a3[o] = fmaf(wv, h3, a3[o]);
                a4[o] = fmaf(wv, h4, a4[o]);
            }
        }
    }

    // ---- SSIM map + local sum. ----
    float lsum = 0.f;
    #pragma unroll
    for (int o = 0; o < S_; ++o) {
        const float mp = a0[o], mt = a1[o];
        const float mp2 = mp * mp, mt2 = mt * mt, mpt = mp * mt;
        const float sp2 = fmaxf(a2[o] - mp2, 0.f);
        const float st2 = fmaxf(a3[o] - mt2, 0.f);
        const float spt = a4[o] - mpt;
        const float num = (2.f * mpt + 1e-4f) * (2.f * spt + 9e-4f);
        const float den = (mp2 + mt2 + 1e-4f) * (sp2 + st2 + 9e-4f);
        lsum += num / (den + 1e-8f);
    }

    // ---- Reduce: wave shuffle -> LDS -> one atomic, ticket finisher. ----
    #pragma unroll
    for (int off = 32; off > 0; off >>= 1)
        lsum += __shfl_down(lsum, off, 64);
    const int wid = tid >> 6, lane = tid & 63;
    if (lane == 0) wsum[wid] = lsum;
    __syncthreads();
    if (tid == 0) {
        const double s = (double)wsum[0] + (double)wsum[1]
                       + (double)wsum[2] + (double)wsum[3];
        atomicAdd(acc, s);
        __threadfence();
        const unsigned int old = atomicAdd(cnt, 1u);
        if (old == (unsigned int)(NBLK - 1)) {
            __threadfence();
            const double tot = atomicAdd(acc, 0.0);   // coherent read
            const double n = (double)B_ * (double)H_ * (double)W_;
            out[0] = (float)(1.0 - tot / n);
        }
    }
}

extern "C" void kernel_launch(void* const* d_in, const int* in_sizes, int n_in,
                              void* d_out, int out_size, void* d_ws, size_t ws_size,
                              hipStream_t stream)
{
    const float* pred = (const float*)d_in[0];
    const float* targ = (const float*)d_in[1];
    const float* win  = (const float*)d_in[2];
    float* out = (float*)d_out;
    double* acc        = (double*)d_ws;
    unsigned int* cnt  = (unsigned int*)((char*)d_ws + sizeof(double));

    hipMemsetAsync(d_ws, 0, 16, stream);
    ssim_fused<<<NBLK, 256, 0, stream>>>(pred, targ, win, acc, cnt, out);
}

// Round 3
// 175.184 us; speedup vs baseline: 1.1205x; 1.0653x over previous
//
#include <hip/hip_runtime.h>

// Fused SSIM loss. B=32, C=1, 512x512, 11x11 separable Gaussian.
// Scanline structure: raw p/t tile in LDS, per-thread horizontal blur
// (ds_read2-friendly), vertical scatter into an 11-deep register ring
// (55 accumulators), SSIM completed inline as each output row finishes.
#define B_   32
#define H_   512
#define W_   512
#define TW   64
#define TH   64
#define SR   16              // output rows per thread strip
#define SCAN (SR + 10)       // 26 h-rows scanned per thread
#define RROWS (TH + 10)      // 74 raw rows staged
#define LDW  76              // LDS row stride (floats)
#define NBLK (B_ * (W_/TW) * (H_/TH))   // 32*8*8 = 2048

__global__ __launch_bounds__(256, 3)
void ssim_fused(const float* __restrict__ pred,
                const float* __restrict__ targ,
                const float* __restrict__ win,
                double* __restrict__ acc,
                unsigned int* __restrict__ cnt,
                float* __restrict__ out)
{
    __shared__ float sp[RROWS][LDW];
    __shared__ float st[RROWS][LDW];
    __shared__ float wg[12];
    __shared__ float wsum[4];

    const int tid = threadIdx.x;
    const int bid = blockIdx.x;
    const int b   = bid >> 6;        // 8x8 tiles of 64x64 per image
    const int rem = bid & 63;
    const int ty  = rem >> 3;
    const int tx  = rem & 7;
    const int x0  = tx * TW - 5;
    const int y0  = ty * TH - 5;

    // 1-D gaussian = row sums of 2-D window (window sums to 1).
    if (tid < 11) {
        float s = 0.f;
        #pragma unroll
        for (int j = 0; j < 11; ++j) s += win[tid * 11 + j];
        wg[tid] = s;
    }

    const float* pb = pred + (size_t)b * (H_ * W_);
    const float* tb = targ + (size_t)b * (H_ * W_);

    // Stage raw tiles, zero-padded outside image (SAME conv semantics).
    for (int i = tid; i < RROWS * LDW; i += 256) {
        const int ly = i / LDW;
        const int lc = i - ly * LDW;
        const int gy = y0 + ly, gx = x0 + lc;
        float p = 0.f, t = 0.f;
        if ((unsigned)gy < (unsigned)H_ && (unsigned)gx < (unsigned)W_) {
            const size_t off = (size_t)gy * W_ + gx;
            p = pb[off];
            t = tb[off];
        }
        sp[ly][lc] = p;
        st[ly][lc] = t;
    }
    __syncthreads();

    float w[11];
    #pragma unroll
    for (int k = 0; k < 11; ++k) w[k] = wg[k];

    const int lx    = tid & 63;          // output column within tile
    const int rbase = (tid >> 6) * SR;   // first raw row of this strip

    // Ring of 11 pending output rows x 5 quantities (static indices).
    float a0[11], a1[11], a2[11], a3[11], a4[11];
    #pragma unroll
    for (int r = 0; r < 11; ++r) {
        a0[r] = 0.f; a1[r] = 0.f; a2[r] = 0.f; a3[r] = 0.f; a4[r] = 0.f;
    }

    float lsum = 0.f;

    #pragma unroll
    for (int j = 0; j < SCAN; ++j) {
        const float* pr = &sp[rbase + j][lx];
        const float* tr = &st[rbase + j][lx];
        // Horizontal 11-tap blur of p, t, p^2, t^2, p*t at this h-row.
        float h0 = 0.f, h1 = 0.f, h2 = 0.f, h3 = 0.f, h4 = 0.f;
        #pragma unroll
        for (int k = 0; k < 11; ++k) {
            const float p = pr[k];
            const float t = tr[k];
            const float wv = w[k];
            const float wp = wv * p;
            const float wt = wv * t;
            h0 += wp;
            h1 += wt;
            h2 = fmaf(wp, p, h2);
            h3 = fmaf(wt, t, h3);
            h4 = fmaf(wp, t, h4);
        }
        // Vertical scatter: output row o uses h-rows o..o+10, weight w[j-o].
        #pragma unroll
        for (int o = 0; o < SR; ++o) {
            if (o <= j && (j - o) < 11) {      // folds to constants
                const int r = o - (o >= 11 ? 11 : 0);  // o % 11, static
                const float wv = w[j - o];
                a0[r] = fmaf(wv, h0, a0[r]);
                a1[r] = fmaf(wv, h1, a1[r]);
                a2[r] = fmaf(wv, h2, a2[r]);
                a3[r] = fmaf(wv, h3, a3[r]);
                a4[r] = fmaf(wv, h4, a4[r]);
            }
        }
        // Output row (j-10) is now complete: SSIM, accumulate, free slot.
        if (j >= 10) {
            const int o = j - 10;
            const int r = o - (o >= 11 ? 11 : 0);      // o % 11, static
            const float mp = a0[r], mt = a1[r];
            const float mp2 = mp * mp, mt2 = mt * mt, mpt = mp * mt;
            const float vp = fmaxf(a2[r] - mp2, 0.f);
            const float vt = fmaxf(a3[r] - mt2, 0.f);
            const float cv = a4[r] - mpt;
            const float num = (2.f * mpt + 1e-4f) * (2.f * cv + 9e-4f);
            const float den = (mp2 + mt2 + 1e-4f) * (vp + vt + 9e-4f);
            lsum += num * __builtin_amdgcn_rcpf(den + 1e-8f);
            a0[r] = 0.f; a1[r] = 0.f; a2[r] = 0.f; a3[r] = 0.f; a4[r] = 0.f;
        }
    }

    // Reduce: wave shuffle -> LDS -> one atomic; ticket finisher.
    #pragma unroll
    for (int off = 32; off > 0; off >>= 1)
        lsum += __shfl_down(lsum, off, 64);
    const int wid = tid >> 6, lane = tid & 63;
    if (lane == 0) wsum[wid] = lsum;
    __syncthreads();
    if (tid == 0) {
        const double s = (double)wsum[0] + (double)wsum[1]
                       + (double)wsum[2] + (double)wsum[3];
        atomicAdd(acc, s);
        __threadfence();
        const unsigned int old = atomicAdd(cnt, 1u);
        if (old == (unsigned int)(NBLK - 1)) {
            __threadfence();
            const double tot = atomicAdd(acc, 0.0);   // coherent read
            const double n = (double)B_ * (double)H_ * (double)W_;
            out[0] = (float)(1.0 - tot / n);
        }
    }
}

extern "C" void kernel_launch(void* const* d_in, const int* in_sizes, int n_in,
                              void* d_out, int out_size, void* d_ws, size_t ws_size,
                              hipStream_t stream)
{
    const float* pred = (const float*)d_in[0];
    const float* targ = (const float*)d_in[1];
    const float* win  = (const float*)d_in[2];
    float* out = (float*)d_out;
    double* acc       = (double*)d_ws;
    unsigned int* cnt = (unsigned int*)((char*)d_ws + sizeof(double));

    hipMemsetAsync(d_ws, 0, 16, stream);
    ssim_fused<<<NBLK, 256, 0, stream>>>(pred, targ, win, acc, cnt, out);
}

// Round 4
// 145.555 us; speedup vs baseline: 1.3485x; 1.2036x over previous
//
#include <hip/hip_runtime.h>

// Fused SSIM loss. B=32, C=1, 512x512, 11x11 separable Gaussian.
// Tile 64x32, raw (p,t) interleaved float2 in LDS (ds_read2_b64-friendly),
// per-thread horizontal blur + register vertical scatter over an 8-row
// strip (float2-packed accumulators -> v_pk_fma_f32), SSIM inline.
// Per-block float partial -> tiny reduce kernel (no memset, no atomics).
typedef float v2f __attribute__((ext_vector_type(2)));

#define B_    32
#define H_    512
#define W_    512
#define TW    64
#define TH    32
#define SR    8              // output rows per thread strip
#define SCAN  (SR + 10)      // 18 h-rows per strip
#define RROWS (TH + 10)      // 42 raw rows staged
#define LDW   76             // LDS row stride (float2 elements)
#define NBLK  (B_ * (W_/TW) * (H_/TH))   // 32*8*16 = 4096

__global__ __launch_bounds__(256, 5)
void ssim_main(const float* __restrict__ pred,
               const float* __restrict__ targ,
               const float* __restrict__ win,
               float* __restrict__ partial)
{
    __shared__ v2f   spt[RROWS][LDW];   // (p,t) pairs, 25.5 KiB
    __shared__ float wg[12];
    __shared__ float wsum[4];

    const int tid = threadIdx.x;
    const int bid = blockIdx.x;
    const int b   = bid >> 7;        // 8x16 = 128 tiles per image
    const int rem = bid & 127;
    const int ty  = rem >> 3;        // 0..15
    const int tx  = rem & 7;         // 0..7
    const int x0  = tx * TW - 5;
    const int y0  = ty * TH - 5;

    // 1-D gaussian = row sums of the 2-D window (window sums to 1).
    if (tid < 11) {
        float s = 0.f;
        #pragma unroll
        for (int j = 0; j < 11; ++j) s += win[tid * 11 + j];
        wg[tid] = s;
    }

    const float* pb = pred + (size_t)b * (H_ * W_);
    const float* tb = targ + (size_t)b * (H_ * W_);

    // ---- Stage interleaved raw tile, zero-padded (SAME conv). ----
    const bool interior = (tx > 0) & (tx < 7) & (ty > 0) & (ty < 15);
    if (interior) {
        for (int i = tid; i < RROWS * LDW; i += 256) {
            const int ly = i / LDW;
            const int lc = i - ly * LDW;
            const size_t off = (size_t)(y0 + ly) * W_ + (x0 + lc);
            v2f v;
            v.x = pb[off];
            v.y = tb[off];
            spt[ly][lc] = v;
        }
    } else {
        for (int i = tid; i < RROWS * LDW; i += 256) {
            const int ly = i / LDW;
            const int lc = i - ly * LDW;
            const int gy = y0 + ly, gx = x0 + lc;
            v2f v = {0.f, 0.f};
            if ((unsigned)gy < (unsigned)H_ && (unsigned)gx < (unsigned)W_) {
                const size_t off = (size_t)gy * W_ + gx;
                v.x = pb[off];
                v.y = tb[off];
            }
            spt[ly][lc] = v;
        }
    }
    __syncthreads();

    float w[11];
    #pragma unroll
    for (int k = 0; k < 11; ++k) w[k] = wg[k];

    const int lx    = tid & 63;          // output column
    const int rbase = (tid >> 6) * SR;   // first raw row of strip

    v2f   A01[SR], A23[SR];   // (mu_p, mu_t), (E p^2, E t^2) pending rows
    float A4[SR];             // E p*t
    #pragma unroll
    for (int o = 0; o < SR; ++o) {
        A01[o] = (v2f){0.f, 0.f};
        A23[o] = (v2f){0.f, 0.f};
        A4[o]  = 0.f;
    }

    float lsum = 0.f;

    #pragma unroll
    for (int j = 0; j < SCAN; ++j) {
        const v2f* row = &spt[rbase + j][lx];
        // Horizontal 11-tap blur of (p,t), (p^2,t^2), p*t.
        v2f h01 = {0.f, 0.f}, h23 = {0.f, 0.f};
        float h4 = 0.f;
        #pragma unroll
        for (int k = 0; k < 11; ++k) {
            const v2f pt = row[k];
            const v2f wv = {w[k], w[k]};
            h01 += wv * pt;               // pk_fma
            h23 += wv * (pt * pt);        // pk_mul + pk_fma
            h4   = fmaf(w[k], pt.x * pt.y, h4);
        }
        // Vertical scatter: output row o uses h-rows o..o+10 (static folds).
        #pragma unroll
        for (int o = 0; o < SR; ++o) {
            if (o <= j && (j - o) < 11) {
                const float wk = w[j - o];
                const v2f wk2 = {wk, wk};
                A01[o] += wk2 * h01;
                A23[o] += wk2 * h23;
                A4[o]   = fmaf(wk, h4, A4[o]);
            }
        }
        // Output row j-10 complete: SSIM, accumulate.
        if (j >= 10) {
            const int o = j - 10;
            const float mp = A01[o].x, mt = A01[o].y;
            const float mp2 = mp * mp, mt2 = mt * mt, mpt = mp * mt;
            const float vp = fmaxf(A23[o].x - mp2, 0.f);
            const float vt = fmaxf(A23[o].y - mt2, 0.f);
            const float cv = A4[o] - mpt;
            const float num = (2.f * mpt + 1e-4f) * (2.f * cv + 9e-4f);
            const float den = (mp2 + mt2 + 1e-4f) * (vp + vt + 9e-4f);
            lsum += num * __builtin_amdgcn_rcpf(den + 1e-8f);
        }
    }

    // ---- Block reduce -> one float partial per block. ----
    #pragma unroll
    for (int off = 32; off > 0; off >>= 1)
        lsum += __shfl_down(lsum, off, 64);
    const int wid = tid >> 6, lane = tid & 63;
    if (lane == 0) wsum[wid] = lsum;
    __syncthreads();
    if (tid == 0)
        partial[bid] = wsum[0] + wsum[1] + wsum[2] + wsum[3];
}

__global__ __launch_bounds__(256)
void ssim_reduce(const float* __restrict__ partial, float* __restrict__ out)
{
    __shared__ double ws[4];
    double s = 0.0;
    for (int i = threadIdx.x; i < NBLK; i += 256) s += (double)partial[i];
    #pragma unroll
    for (int off = 32; off > 0; off >>= 1)
        s += __shfl_down(s, off, 64);
    if ((threadIdx.x & 63) == 0) ws[threadIdx.x >> 6] = s;
    __syncthreads();
    if (threadIdx.x == 0) {
        const double tot = ws[0] + ws[1] + ws[2] + ws[3];
        const double n = (double)B_ * (double)H_ * (double)W_;
        out[0] = (float)(1.0 - tot / n);
    }
}

extern "C" void kernel_launch(void* const* d_in, const int* in_sizes, int n_in,
                              void* d_out, int out_size, void* d_ws, size_t ws_size,
                              hipStream_t stream)
{
    const float* pred = (const float*)d_in[0];
    const float* targ = (const float*)d_in[1];
    const float* win  = (const float*)d_in[2];
    float* out     = (float*)d_out;
    float* partial = (float*)d_ws;      // NBLK floats = 16 KiB scratch

    ssim_main<<<NBLK, 256, 0, stream>>>(pred, targ, win, partial);
    ssim_reduce<<<1, 256, 0, stream>>>(partial, out);
}